// Round 11
// baseline (491.257 us; speedup 1.0000x reference)
//
#include <hip/hip_runtime.h>
#include <math.h>

// B=32, R=16384, C=16, IC=16, OC=16, 3 routing iterations.
// x: (B,C,IC) fp32 [8192]; W: (R,C,OC,IC) fp32 [67108864 = 256 MB]; out: (B,C,OC) fp32.
//
// Algebra 1: b after iter2 = <u,v1>, after iter3 = <u,v1+v2> -> no logit array.
// Algebra 2: iter-1 is the same streaming kernel with uniform weights (MODE 0).
//
// Structure (R10, best=488us): mfma_f32_32x32x16_f16 packs TWO routes (M=32)
// x all 32 b (N=32), K=16=IC. W streamed global->VGPR (zero reuse -> no LDS).
// 2-term fp16 split: u = hh + (hl+lh)/2048, residual ~2^-22.
// R11 diet: (a) chain the split through the MFMA C-operand
//     t = Ah*Bl; t = Al*Bh + t; t *= 1/2048; u = Ah*Bh + t
//   -> kills the 2nd 16-reg accumulator + the 16-op combine;
// (b) #pragma unroll 1 on the pair loop (R9 lesson: unroll doubles temps and
//   blows the 128-arch cap -> AGPR shuttle/spill tax; R10 likely still paid
//   a residual: ~150us/pass vs 41us HBM floor with live ~150 at unroll 2).
// Peak live now ~95 regs < 128 cap of launch_bounds(512,2).

typedef _Float16 half8_t __attribute__((ext_vector_type(8)));
typedef float f32x16_t __attribute__((ext_vector_type(16)));

// ---------------------------------------------------------------------------
// k_v1: v1 = squash(S / R), S = E1[b,c,o] (sum over r of u, from MODE-0 pass)
// ---------------------------------------------------------------------------
__global__ __launch_bounds__(256) void k_v1(const float* __restrict__ E1,
                                            float* __restrict__ v1) {
    int t = blockIdx.x * 256 + threadIdx.x;        // 0..8191
    float s = E1[t] * (1.0f / 16384.0f);
    float ns = s * s;
    #pragma unroll
    for (int d = 1; d < 16; d <<= 1) ns += __shfl_xor(ns, d);
    v1[t] = s * (sqrtf(ns) / (1.0f + ns));
}

// k_vsum: v2 = squash(E/Z); vsum = v1 + v2
__global__ __launch_bounds__(256) void k_vsum(const float* __restrict__ E,
                                              const float* __restrict__ Z,
                                              const float* __restrict__ v1,
                                              float* __restrict__ vsum) {
    int t = blockIdx.x * 256 + threadIdx.x;
    float s = E[t] / Z[t >> 4];
    float ns = s * s;
    #pragma unroll
    for (int d = 1; d < 16; d <<= 1) ns += __shfl_xor(ns, d);
    vsum[t] = v1[t] + s * (sqrtf(ns) / (1.0f + ns));
}

// k_vout: final v = squash(E/Z) -> out
__global__ __launch_bounds__(256) void k_vout(const float* __restrict__ E,
                                              const float* __restrict__ Z,
                                              float* __restrict__ dst) {
    int t = blockIdx.x * 256 + threadIdx.x;
    float s = E[t] / Z[t >> 4];
    float ns = s * s;
    #pragma unroll
    for (int d = 1; d < 16; d <<= 1) ns += __shfl_xor(ns, d);
    dst[t] = s * (sqrtf(ns) / (1.0f + ns));
}

// ---------------------------------------------------------------------------
// k_route<MODE,REV>: one W-streaming pass via paired-route MFMA, LDS-free
// main loop.  Block 512 = 8 waves; grid (64 bx, 16 c).  Wave wv owns routes
// r0+wv*32 .. +31 = 16 pairs.  Per pair p (routes 2p, 2p+1):
//   A[m=32][k=16]: m<16 -> route-even o=m; m>=16 -> route-odd o=m-16.
//     lane l holds m=l&31, k=8*(l>>5)+j  -> 2 global float4 loads per lane
//     from row (2p + ((l>>4)&1)) at float (l&15)*16 + (l>>5)*8.
//   B[k=16][n=32]: n = b = l&31, k = 8*(l>>5)+j (from x, loaded once).
//   Chained-C split: t = Ah*Bl; t = Al*Bh + t; t *= 1/2048; u = Ah*Bh + t.
//   D-layout (HW-verified): lane -> b=lane&31; reg j -> row=(j&3)+8*(j>>2)+
//   4*(lane>>5); row<16 = route-even o=row, row>=16 = route-odd o=row-16.
//   MODE 1: Lv per parity = 8 lane-local fma + shfl_xor(32); e = exp(Lv);
//           accE[16] += e*u (lane-local); accZ += e.
//   MODE 0: a1,a2 carry across all pairs (C-in=C-out); extract once at end.
// Prefetch depth 2 pairs in named registers; #pragma unroll 1 keeps one
// body's temporaries live (reg diet). REV: reverse bx for L3 tail reuse.
// ---------------------------------------------------------------------------
template <int MODE, int REV>
__global__ __launch_bounds__(512, 2)
void k_route(const float* __restrict__ W,
             const float* __restrict__ x,
             const float* __restrict__ v,
             float* __restrict__ E,
             float* __restrict__ Z) {
    __shared__ float red[8 * 512 + 256];           // 17 KB epilogue scratch
    const int c = blockIdx.y;
    const int bx = REV ? (63 - (int)blockIdx.x) : (int)blockIdx.x;
    const int r0 = bx * 256;
    const int tid = threadIdx.x;
    const int wv = tid >> 6;                       // [0,8)
    const int lane = tid & 63;
    const int b = lane & 31;                       // batch (N-col / D-col)
    const int kh = lane >> 5;                      // k-half

    // ---- B fragments from x (loaded once; fp16 split) ----
    half8_t Bh, Bl;
    {
        const float4* xb = (const float4*)(x + (b * 16 + c) * 16) + kh * 2;
        float4 x0 = xb[0], x1 = xb[1];
        float xv[8] = {x0.x, x0.y, x0.z, x0.w, x1.x, x1.y, x1.z, x1.w};
        #pragma unroll
        for (int j = 0; j < 8; ++j) {
            _Float16 h = (_Float16)xv[j];
            Bh[j] = h;
            Bl[j] = (_Float16)((xv[j] - (float)h) * 2048.0f);
        }
    }
    // v slice for this lane: o in {4kh..4kh+3} u {8+4kh..11+4kh}
    float vv[8];
    if (MODE) {
        const float4* vb = (const float4*)(v + (b * 16 + c) * 16);
        float4 v0 = vb[kh], v1 = vb[2 + kh];
        vv[0]=v0.x; vv[1]=v0.y; vv[2]=v0.z; vv[3]=v0.w;
        vv[4]=v1.x; vv[5]=v1.y; vv[6]=v1.z; vv[7]=v1.w;
    }

    f32x16_t a1 = {0.f,0.f,0.f,0.f,0.f,0.f,0.f,0.f,
                   0.f,0.f,0.f,0.f,0.f,0.f,0.f,0.f};
    f32x16_t a2 = a1;
    const f32x16_t z16 = a1;
    float accE[16];
    #pragma unroll
    for (int j = 0; j < 16; ++j) accE[j] = 0.f;
    float accZ0 = 0.f, accZ1 = 0.f;

    // per-lane W pointer: pair p -> route r0 + wv*32 + 2p + ((lane>>4)&1)
    const int rsel = (lane >> 4) & 1;
    const float4* wp = (const float4*)W
        + ((size_t)(r0 + wv * 32 + rsel) * 16 + c) * 64
        + (lane & 15) * 4 + kh * 2;
    const size_t PSTR = 2 * 16 * 64;               // 2 routes in float4s

    float4 n0a = wp[0], n0b = wp[1];               // prefetch pair 0
    float4 n1a = wp[PSTR], n1b = wp[PSTR + 1];     // prefetch pair 1

    #pragma unroll 1
    for (int p = 0; p < 16; ++p) {
        float4 wa = n0a, wb = n0b;
        n0a = n1a; n0b = n1b;
        if (p + 2 < 16) {                          // issue pair p+2 loads
            const float4* np = wp + (size_t)(p + 2) * PSTR;
            n1a = np[0]; n1b = np[1];
        }
        float wf[8] = {wa.x, wa.y, wa.z, wa.w, wb.x, wb.y, wb.z, wb.w};
        half8_t Ah, Al;
        #pragma unroll
        for (int j = 0; j < 8; ++j) {
            _Float16 h = (_Float16)wf[j];
            Ah[j] = h;
            Al[j] = (_Float16)((wf[j] - (float)h) * 2048.0f);
        }
        if (MODE) {
            // chained-C split: one 16-reg accumulator total
            f32x16_t t = __builtin_amdgcn_mfma_f32_32x32x16_f16(Ah, Bl, z16, 0, 0, 0);
            t = __builtin_amdgcn_mfma_f32_32x32x16_f16(Al, Bh, t, 0, 0, 0);
            #pragma unroll
            for (int j = 0; j < 16; ++j) t[j] *= (1.0f / 2048.0f);
            t = __builtin_amdgcn_mfma_f32_32x32x16_f16(Ah, Bh, t, 0, 0, 0);
            float pe = 0.f, po = 0.f;
            #pragma unroll
            for (int rb = 0; rb < 4; ++rb) {
                pe += t[rb] * vv[rb] + t[4 + rb] * vv[4 + rb];
                po += t[8 + rb] * vv[rb] + t[12 + rb] * vv[4 + rb];
            }
            pe += __shfl_xor(pe, 32);              // join k-halves (o-halves)
            po += __shfl_xor(po, 32);
            float e0 = __expf(pe), e1 = __expf(po);
            accZ0 += e0;  accZ1 += e1;
            #pragma unroll
            for (int j = 0; j < 8; ++j)  accE[j] += e0 * t[j];
            #pragma unroll
            for (int j = 8; j < 16; ++j) accE[j] += e1 * t[j];
        } else {
            a1 = __builtin_amdgcn_mfma_f32_32x32x16_f16(Ah, Bh, a1, 0, 0, 0);
            a2 = __builtin_amdgcn_mfma_f32_32x32x16_f16(Ah, Bl, a2, 0, 0, 0);
            a2 = __builtin_amdgcn_mfma_f32_32x32x16_f16(Al, Bh, a2, 0, 0, 0);
        }
    }
    if (!MODE) {
        #pragma unroll
        for (int j = 0; j < 16; ++j) accE[j] = a1[j] + a2[j] * (1.0f / 2048.0f);
    }

    // fold route parities: contribution to E[b,c,o]:
    //   o = 4kh+rb    <- accE[rb]   + accE[8+rb]
    //   o = 8+4kh+rb  <- accE[4+rb] + accE[12+rb]
    float4 e0 = make_float4(accE[0] + accE[8],  accE[1] + accE[9],
                            accE[2] + accE[10], accE[3] + accE[11]);
    float4 e1 = make_float4(accE[4] + accE[12], accE[5] + accE[13],
                            accE[6] + accE[14], accE[7] + accE[15]);
    *(float4*)&red[wv * 512 + b * 16 + 4 * kh]     = e0;
    *(float4*)&red[wv * 512 + b * 16 + 8 + 4 * kh] = e1;
    if (MODE && kh == 0) red[4096 + wv * 32 + b] = accZ0 + accZ1;
    __syncthreads();
    {
        float s = 0.f;
        #pragma unroll
        for (int w2 = 0; w2 < 8; ++w2) s += red[w2 * 512 + tid];
        atomicAdd(&E[(tid >> 4) * 256 + c * 16 + (tid & 15)], s);
    }
    if (MODE && tid < 32) {
        float sz = 0.f;
        #pragma unroll
        for (int w2 = 0; w2 < 8; ++w2) sz += red[4096 + w2 * 32 + tid];
        atomicAdd(&Z[tid * 16 + c], sz);
    }
}

// ---------------------------------------------------------------------------
// launch
// ---------------------------------------------------------------------------
extern "C" void kernel_launch(void* const* d_in, const int* in_sizes, int n_in,
                              void* d_out, int out_size, void* d_ws, size_t ws_size,
                              hipStream_t stream) {
    const float* x = (const float*)d_in[0];        // 8192 floats
    const float* W = (const float*)d_in[1];        // 67108864 floats (256 MB)
    float* out = (float*)d_out;                    // 8192 floats
    float* ws = (float*)d_ws;

    float* E1   = ws + 0;          // 8192  (S = sum_r u)
    float* E2   = ws + 8192;       // 8192
    float* Z2   = ws + 16384;      // 512
    float* E3   = ws + 16896;      // 8192
    float* Z3   = ws + 25088;      // 512   (zeroed region ends at 25600)
    float* v1   = ws + 25600;      // 8192
    float* vsum = ws + 33792;      // 8192

    hipMemsetAsync(ws, 0, 25600 * sizeof(float), stream);

    // iter 1: S = sum_r u (uniform routing), W pass 1 (forward r)
    k_route<0, 0><<<dim3(64, 16), 512, 0, stream>>>(W, x, v1, E1, Z2);
    k_v1<<<32, 256, 0, stream>>>(E1, v1);          // v1 = squash(S/R)

    // iter 2: logits = <u, v1>, W pass 2 (reverse r for L3 tail reuse)
    k_route<1, 1><<<dim3(64, 16), 512, 0, stream>>>(W, x, v1, E2, Z2);
    k_vsum<<<32, 256, 0, stream>>>(E2, Z2, v1, vsum);  // vsum = v1 + squash(E2/Z2)

    // iter 3: logits = <u, v1+v2>, W pass 3 (forward r)
    k_route<1, 0><<<dim3(64, 16), 512, 0, stream>>>(W, x, vsum, E3, Z3);
    k_vout<<<32, 256, 0, stream>>>(E3, Z3, out);
}

// Round 13
// 480.220 us; speedup vs baseline: 1.0230x; 1.0230x over previous
//
#include <hip/hip_runtime.h>
#include <math.h>

// B=32, R=16384, C=16, IC=16, OC=16, 3 routing iterations.
// x: (B,C,IC) fp32 [8192]; W: (R,C,OC,IC) fp32 [67108864 = 256 MB]; out: (B,C,OC) fp32.
//
// Algebra 1: b after iter2 = <u,v1>, after iter3 = <u,v1+v2> -> no logit array.
// Algebra 2: iter-1 is the same streaming kernel with uniform weights (MODE 0).
//
// Structure (R10/R11, best=488us, absmax 1.9e-6): mfma_f32_32x32x16_f16 packs
// TWO routes (M=32) x all 32 b (N=32), K=16=IC. W streamed global->VGPR.
// 2-term fp16 split chained through the MFMA C operand.
//
// R13 single change: grid (64,16)->(16,64) with c = blockIdx.x (fastest).
// Rationale: R9 counters show the MFMA structure runs AT the bandwidth it
// gets (dur = bytes / 2.77 TB/s) but only ~45% DRAM efficiency. With bx
// fastest, co-resident blocks = many bx at the same c -> device-wide gather
// of 1 KB used per 16 KB stride (c-slice per route) -> page-activate per KB.
// With c fastest, the 16 c-blocks of one 4 MB route window run concurrently
// and their union is CONTIGUOUS -> DRAM page locality restored.
// R12 lesson: cooperative launch silently no-ops under graph capture (dur=NaN,
// out=0) -- do not use hipLaunchCooperativeKernel in this harness.

typedef _Float16 half8_t __attribute__((ext_vector_type(8)));
typedef float f32x16_t __attribute__((ext_vector_type(16)));

// ---------------------------------------------------------------------------
// k_v1: v1 = squash(S / R), S = E1[b,c,o] (sum over r of u, from MODE-0 pass)
// ---------------------------------------------------------------------------
__global__ __launch_bounds__(256) void k_v1(const float* __restrict__ E1,
                                            float* __restrict__ v1) {
    int t = blockIdx.x * 256 + threadIdx.x;        // 0..8191
    float s = E1[t] * (1.0f / 16384.0f);
    float ns = s * s;
    #pragma unroll
    for (int d = 1; d < 16; d <<= 1) ns += __shfl_xor(ns, d);
    v1[t] = s * (sqrtf(ns) / (1.0f + ns));
}

// k_vsum: v2 = squash(E/Z); vsum = v1 + v2
__global__ __launch_bounds__(256) void k_vsum(const float* __restrict__ E,
                                              const float* __restrict__ Z,
                                              const float* __restrict__ v1,
                                              float* __restrict__ vsum) {
    int t = blockIdx.x * 256 + threadIdx.x;
    float s = E[t] / Z[t >> 4];
    float ns = s * s;
    #pragma unroll
    for (int d = 1; d < 16; d <<= 1) ns += __shfl_xor(ns, d);
    vsum[t] = v1[t] + s * (sqrtf(ns) / (1.0f + ns));
}

// k_vout: final v = squash(E/Z) -> out
__global__ __launch_bounds__(256) void k_vout(const float* __restrict__ E,
                                              const float* __restrict__ Z,
                                              float* __restrict__ dst) {
    int t = blockIdx.x * 256 + threadIdx.x;
    float s = E[t] / Z[t >> 4];
    float ns = s * s;
    #pragma unroll
    for (int d = 1; d < 16; d <<= 1) ns += __shfl_xor(ns, d);
    dst[t] = s * (sqrtf(ns) / (1.0f + ns));
}

// ---------------------------------------------------------------------------
// k_route<MODE,REV>: one W-streaming pass via paired-route MFMA, LDS-free
// main loop.  Block 512 = 8 waves; grid (16 c, 64 bx).  Wave wv owns routes
// r0+wv*32 .. +31 = 16 pairs.  Per pair p (routes 2p, 2p+1):
//   A[m=32][k=16]: m<16 -> route-even o=m; m>=16 -> route-odd o=m-16.
//     lane l holds m=l&31, k=8*(l>>5)+j  -> 2 global float4 loads per lane
//     from row (2p + ((l>>4)&1)) at float (l&15)*16 + (l>>5)*8.
//   B[k=16][n=32]: n = b = l&31, k = 8*(l>>5)+j (from x, loaded once).
//   Chained-C split: t = Ah*Bl; t = Al*Bh + t; t *= 1/2048; u = Ah*Bh + t.
//   D-layout (HW-verified): lane -> b=lane&31; reg j -> row=(j&3)+8*(j>>2)+
//   4*(lane>>5); row<16 = route-even o=row, row>=16 = route-odd o=row-16.
//   MODE 1: Lv per parity = 8 lane-local fma + shfl_xor(32); e = exp(Lv);
//           accE[16] += e*u (lane-local); accZ += e.
//   MODE 0: a1,a2 carry across all pairs (C-in=C-out); extract once at end.
// Prefetch depth 2 pairs in named registers; #pragma unroll 1 keeps one
// body's temporaries live. REV: reverse bx for L3 tail reuse between passes.
// ---------------------------------------------------------------------------
template <int MODE, int REV>
__global__ __launch_bounds__(512, 2)
void k_route(const float* __restrict__ W,
             const float* __restrict__ x,
             const float* __restrict__ v,
             float* __restrict__ E,
             float* __restrict__ Z) {
    __shared__ float red[8 * 512 + 256];           // 17 KB epilogue scratch
    const int c = blockIdx.x;                      // fastest-varying: 16 c's
    const int bxr = (int)blockIdx.y;               // of one route window run
    const int bx = REV ? (63 - bxr) : bxr;         // concurrently (contiguous
    const int r0 = bx * 256;                       // 4 MB DRAM span)
    const int tid = threadIdx.x;
    const int wv = tid >> 6;                       // [0,8)
    const int lane = tid & 63;
    const int b = lane & 31;                       // batch (N-col / D-col)
    const int kh = lane >> 5;                      // k-half

    // ---- B fragments from x (loaded once; fp16 split) ----
    half8_t Bh, Bl;
    {
        const float4* xb = (const float4*)(x + (b * 16 + c) * 16) + kh * 2;
        float4 x0 = xb[0], x1 = xb[1];
        float xv[8] = {x0.x, x0.y, x0.z, x0.w, x1.x, x1.y, x1.z, x1.w};
        #pragma unroll
        for (int j = 0; j < 8; ++j) {
            _Float16 h = (_Float16)xv[j];
            Bh[j] = h;
            Bl[j] = (_Float16)((xv[j] - (float)h) * 2048.0f);
        }
    }
    // v slice for this lane: o in {4kh..4kh+3} u {8+4kh..11+4kh}
    float vv[8];
    if (MODE) {
        const float4* vb = (const float4*)(v + (b * 16 + c) * 16);
        float4 v0 = vb[kh], v1 = vb[2 + kh];
        vv[0]=v0.x; vv[1]=v0.y; vv[2]=v0.z; vv[3]=v0.w;
        vv[4]=v1.x; vv[5]=v1.y; vv[6]=v1.z; vv[7]=v1.w;
    }

    f32x16_t a1 = {0.f,0.f,0.f,0.f,0.f,0.f,0.f,0.f,
                   0.f,0.f,0.f,0.f,0.f,0.f,0.f,0.f};
    f32x16_t a2 = a1;
    const f32x16_t z16 = a1;
    float accE[16];
    #pragma unroll
    for (int j = 0; j < 16; ++j) accE[j] = 0.f;
    float accZ0 = 0.f, accZ1 = 0.f;

    // per-lane W pointer: pair p -> route r0 + wv*32 + 2p + ((lane>>4)&1)
    const int rsel = (lane >> 4) & 1;
    const float4* wp = (const float4*)W
        + ((size_t)(r0 + wv * 32 + rsel) * 16 + c) * 64
        + (lane & 15) * 4 + kh * 2;
    const size_t PSTR = 2 * 16 * 64;               // 2 routes in float4s

    float4 n0a = wp[0], n0b = wp[1];               // prefetch pair 0
    float4 n1a = wp[PSTR], n1b = wp[PSTR + 1];     // prefetch pair 1

    #pragma unroll 1
    for (int p = 0; p < 16; ++p) {
        float4 wa = n0a, wb = n0b;
        n0a = n1a; n0b = n1b;
        if (p + 2 < 16) {                          // issue pair p+2 loads
            const float4* np = wp + (size_t)(p + 2) * PSTR;
            n1a = np[0]; n1b = np[1];
        }
        float wf[8] = {wa.x, wa.y, wa.z, wa.w, wb.x, wb.y, wb.z, wb.w};
        half8_t Ah, Al;
        #pragma unroll
        for (int j = 0; j < 8; ++j) {
            _Float16 h = (_Float16)wf[j];
            Ah[j] = h;
            Al[j] = (_Float16)((wf[j] - (float)h) * 2048.0f);
        }
        if (MODE) {
            // chained-C split: one 16-reg accumulator total
            f32x16_t t = __builtin_amdgcn_mfma_f32_32x32x16_f16(Ah, Bl, z16, 0, 0, 0);
            t = __builtin_amdgcn_mfma_f32_32x32x16_f16(Al, Bh, t, 0, 0, 0);
            #pragma unroll
            for (int j = 0; j < 16; ++j) t[j] *= (1.0f / 2048.0f);
            t = __builtin_amdgcn_mfma_f32_32x32x16_f16(Ah, Bh, t, 0, 0, 0);
            float pe = 0.f, po = 0.f;
            #pragma unroll
            for (int rb = 0; rb < 4; ++rb) {
                pe += t[rb] * vv[rb] + t[4 + rb] * vv[4 + rb];
                po += t[8 + rb] * vv[rb] + t[12 + rb] * vv[4 + rb];
            }
            pe += __shfl_xor(pe, 32);              // join k-halves (o-halves)
            po += __shfl_xor(po, 32);
            float e0 = __expf(pe), e1 = __expf(po);
            accZ0 += e0;  accZ1 += e1;
            #pragma unroll
            for (int j = 0; j < 8; ++j)  accE[j] += e0 * t[j];
            #pragma unroll
            for (int j = 8; j < 16; ++j) accE[j] += e1 * t[j];
        } else {
            a1 = __builtin_amdgcn_mfma_f32_32x32x16_f16(Ah, Bh, a1, 0, 0, 0);
            a2 = __builtin_amdgcn_mfma_f32_32x32x16_f16(Ah, Bl, a2, 0, 0, 0);
            a2 = __builtin_amdgcn_mfma_f32_32x32x16_f16(Al, Bh, a2, 0, 0, 0);
        }
    }
    if (!MODE) {
        #pragma unroll
        for (int j = 0; j < 16; ++j) accE[j] = a1[j] + a2[j] * (1.0f / 2048.0f);
    }

    // fold route parities: contribution to E[b,c,o]:
    //   o = 4kh+rb    <- accE[rb]   + accE[8+rb]
    //   o = 8+4kh+rb  <- accE[4+rb] + accE[12+rb]
    float4 e0 = make_float4(accE[0] + accE[8],  accE[1] + accE[9],
                            accE[2] + accE[10], accE[3] + accE[11]);
    float4 e1 = make_float4(accE[4] + accE[12], accE[5] + accE[13],
                            accE[6] + accE[14], accE[7] + accE[15]);
    *(float4*)&red[wv * 512 + b * 16 + 4 * kh]     = e0;
    *(float4*)&red[wv * 512 + b * 16 + 8 + 4 * kh] = e1;
    if (MODE && kh == 0) red[4096 + wv * 32 + b] = accZ0 + accZ1;
    __syncthreads();
    {
        float s = 0.f;
        #pragma unroll
        for (int w2 = 0; w2 < 8; ++w2) s += red[w2 * 512 + tid];
        atomicAdd(&E[(tid >> 4) * 256 + c * 16 + (tid & 15)], s);
    }
    if (MODE && tid < 32) {
        float sz = 0.f;
        #pragma unroll
        for (int w2 = 0; w2 < 8; ++w2) sz += red[4096 + w2 * 32 + tid];
        atomicAdd(&Z[tid * 16 + c], sz);
    }
}

// ---------------------------------------------------------------------------
// launch
// ---------------------------------------------------------------------------
extern "C" void kernel_launch(void* const* d_in, const int* in_sizes, int n_in,
                              void* d_out, int out_size, void* d_ws, size_t ws_size,
                              hipStream_t stream) {
    const float* x = (const float*)d_in[0];        // 8192 floats
    const float* W = (const float*)d_in[1];        // 67108864 floats (256 MB)
    float* out = (float*)d_out;                    // 8192 floats
    float* ws = (float*)d_ws;

    float* E1   = ws + 0;          // 8192  (S = sum_r u)
    float* E2   = ws + 8192;       // 8192
    float* Z2   = ws + 16384;      // 512
    float* E3   = ws + 16896;      // 8192
    float* Z3   = ws + 25088;      // 512   (zeroed region ends at 25600)
    float* v1   = ws + 25600;      // 8192
    float* vsum = ws + 33792;      // 8192

    hipMemsetAsync(ws, 0, 25600 * sizeof(float), stream);

    // iter 1: S = sum_r u (uniform routing), W pass 1 (forward r)
    k_route<0, 0><<<dim3(16, 64), 512, 0, stream>>>(W, x, v1, E1, Z2);
    k_v1<<<32, 256, 0, stream>>>(E1, v1);          // v1 = squash(S/R)

    // iter 2: logits = <u, v1>, W pass 2 (reverse r for L3 tail reuse)
    k_route<1, 1><<<dim3(16, 64), 512, 0, stream>>>(W, x, v1, E2, Z2);
    k_vsum<<<32, 256, 0, stream>>>(E2, Z2, v1, vsum);  // vsum = v1 + squash(E2/Z2)

    // iter 3: logits = <u, v1+v2>, W pass 3 (forward r)
    k_route<1, 0><<<dim3(16, 64), 512, 0, stream>>>(W, x, vsum, E3, Z3);
    k_vout<<<32, 256, 0, stream>>>(E3, Z3, out);
}

// Round 14
// 463.876 us; speedup vs baseline: 1.0590x; 1.0352x over previous
//
#include <hip/hip_runtime.h>
#include <math.h>

// B=32, R=16384, C=16, IC=16, OC=16, 3 routing iterations.
// x: (B,C,IC) fp32 [8192]; W: (R,C,OC,IC) fp32 [67108864 = 256 MB]; out: (B,C,OC) fp32.
//
// Algebra 1: b after iter2 = <u,v1>, after iter3 = <u,v1+v2> -> no logit array.
// Algebra 2: iter-1 is the same streaming kernel with uniform weights (MODE 0).
//
// R14 theory: all MFMA rounds pinned at ~1.7-2.8 TB/s effective. Common factor:
// A-fragment gathers (16B/lane at 64B stride over 2 routes 16KB apart = 32
// cache lines per instruction, 25-50% line use, 2 loads in flight per wave).
// Fix: stage W via global_load_lds -- each instruction reads a CONTIGUOUS 1 KB
// route-slice (64 lanes x 16B dense), async DMA (no VGPR hold, deep queue).
// The fragment permutation moves to the per-lane SOURCE chunk index (union
// still covers whole lines -> coalescing kept; both-sides-or-neither rule):
//   source chunk for lane l:  pi(l)   = l ^ ((l>>3)&7)      (involution)
//   read slot for chunk c:    s(c)    = c ^ ((c>>3)&7)  =>  pi(s(c)) = c
// ds_read_b128 fragment reads then hit 8 lanes/bank-quad = conflict-free floor.
// Wave-private double buffers -> NO barrier in main loop; per-wave counted
// s_waitcnt vmcnt(4) (never 0 mid-loop). Math/epilogue = R13 (absmax 4.9e-4).
// R12 lesson: no cooperative launch under graph capture.

typedef _Float16 half8_t __attribute__((ext_vector_type(8)));
typedef float f32x16_t __attribute__((ext_vector_type(16)));

// async global->LDS, 16 B per lane. LDS dest = wave-uniform base + lane*16.
__device__ __forceinline__ void gload_lds16(const void* g, void* l) {
  __builtin_amdgcn_global_load_lds(
      (const __attribute__((address_space(1))) unsigned int*)g,
      (__attribute__((address_space(3))) unsigned int*)l, 16, 0, 0);
}

// ---------------------------------------------------------------------------
// k_v1: v1 = squash(S / R), S = E1[b,c,o] (sum over r of u, from MODE-0 pass)
// ---------------------------------------------------------------------------
__global__ __launch_bounds__(256) void k_v1(const float* __restrict__ E1,
                                            float* __restrict__ v1) {
    int t = blockIdx.x * 256 + threadIdx.x;        // 0..8191
    float s = E1[t] * (1.0f / 16384.0f);
    float ns = s * s;
    #pragma unroll
    for (int d = 1; d < 16; d <<= 1) ns += __shfl_xor(ns, d);
    v1[t] = s * (sqrtf(ns) / (1.0f + ns));
}

// k_vsum: v2 = squash(E/Z); vsum = v1 + v2
__global__ __launch_bounds__(256) void k_vsum(const float* __restrict__ E,
                                              const float* __restrict__ Z,
                                              const float* __restrict__ v1,
                                              float* __restrict__ vsum) {
    int t = blockIdx.x * 256 + threadIdx.x;
    float s = E[t] / Z[t >> 4];
    float ns = s * s;
    #pragma unroll
    for (int d = 1; d < 16; d <<= 1) ns += __shfl_xor(ns, d);
    vsum[t] = v1[t] + s * (sqrtf(ns) / (1.0f + ns));
}

// k_vout: final v = squash(E/Z) -> out
__global__ __launch_bounds__(256) void k_vout(const float* __restrict__ E,
                                              const float* __restrict__ Z,
                                              float* __restrict__ dst) {
    int t = blockIdx.x * 256 + threadIdx.x;
    float s = E[t] / Z[t >> 4];
    float ns = s * s;
    #pragma unroll
    for (int d = 1; d < 16; d <<= 1) ns += __shfl_xor(ns, d);
    dst[t] = s * (sqrtf(ns) / (1.0f + ns));
}

// ---------------------------------------------------------------------------
// k_route<MODE,REV>: one W-streaming pass, paired-route MFMA, DMA-staged W.
// Block 512 = 8 waves; grid (16 c, 64 bx). Wave wv owns routes r0+wv*32..+31
// = 16 pairs, processed as 8 steps x 2 pairs. Per step: stage next step's
// 4 routes (4 x gload_lds16, 1 KB contiguous each) into the wave's OTHER
// 4 KB buffer; vmcnt(4); compute 2 pairs from the current buffer.
//   A-fragment read per pair: lane l needs 32B = chunks c0,c0+1 of the pair's
//   2 KB, c0 = rsel*64 + (l&15)*4 + kh*2 (rsel=(l>>4)&1, kh=l>>5);
//   read slots s0 = c0^((c0>>3)&7), s1 = s0^1 (swizzled layout, see header).
//   Chained-C fp16-split MFMA (R11): t=(AhBl); t=(AlBh)+t; t*=1/2048;
//   t=(AhBh)+t. D-layout: lane->b=lane&31; reg j->row (j&3)+8*(j>>2)+4*kh;
//   row<16 route-even o=row, row>=16 route-odd o=row-16.
//   MODE 1: Lv per parity = 8 fma + shfl_xor(32); e=exp; accE/accZ.
//   MODE 0: a1,a2 MFMA accumulators carry across all pairs.
// Epilogue: LDS tree + atomics (R13-verbatim), red overlays the W buffers.
// ---------------------------------------------------------------------------
template <int MODE, int REV>
__global__ __launch_bounds__(512, 2)
void k_route(const float* __restrict__ W,
             const float* __restrict__ x,
             const float* __restrict__ v,
             float* __restrict__ E,
             float* __restrict__ Z) {
    __shared__ float4 Wl[8][2][256];               // 64 KB: per-wave 2 x 4 KB
    const int c = blockIdx.x;                      // fastest-varying
    const int bxr = (int)blockIdx.y;
    const int bx = REV ? (63 - bxr) : bxr;
    const int r0 = bx * 256;
    const int tid = threadIdx.x;
    const int wv = tid >> 6;                       // [0,8)
    const int lane = tid & 63;
    const int b = lane & 31;                       // batch (N-col / D-col)
    const int kh = lane >> 5;                      // k-half
    const int rsel = (lane >> 4) & 1;              // route parity (A-frag)

    // ---- B fragments from x (loaded once; fp16 split) ----
    half8_t Bh, Bl;
    {
        const float4* xb = (const float4*)(x + (b * 16 + c) * 16) + kh * 2;
        float4 x0 = xb[0], x1 = xb[1];
        float xv[8] = {x0.x, x0.y, x0.z, x0.w, x1.x, x1.y, x1.z, x1.w};
        #pragma unroll
        for (int j = 0; j < 8; ++j) {
            _Float16 h = (_Float16)xv[j];
            Bh[j] = h;
            Bl[j] = (_Float16)((xv[j] - (float)h) * 2048.0f);
        }
    }
    // v slice for this lane: o in {4kh..4kh+3} u {8+4kh..11+4kh}
    float vv[8];
    if (MODE) {
        const float4* vb = (const float4*)(v + (b * 16 + c) * 16);
        float4 v0 = vb[kh], v1 = vb[2 + kh];
        vv[0]=v0.x; vv[1]=v0.y; vv[2]=v0.z; vv[3]=v0.w;
        vv[4]=v1.x; vv[5]=v1.y; vv[6]=v1.z; vv[7]=v1.w;
    }

    f32x16_t a1 = {0.f,0.f,0.f,0.f,0.f,0.f,0.f,0.f,
                   0.f,0.f,0.f,0.f,0.f,0.f,0.f,0.f};
    f32x16_t a2 = a1;
    const f32x16_t z16 = a1;
    float accE[16];
    #pragma unroll
    for (int j = 0; j < 16; ++j) accE[j] = 0.f;
    float accZ0 = 0.f, accZ1 = 0.f;

    const float4* W4 = (const float4*)W;
    const int pi = lane ^ ((lane >> 3) & 7);       // staged source chunk
    // read slots (loop-invariant per lane)
    const int c0 = rsel * 64 + (lane & 15) * 4 + kh * 2;
    const int s0 = c0 ^ ((c0 >> 3) & 7);
    const int s1 = s0 ^ 1;

    // stage step st into buffer bf: 4 routes (2 pairs), 1 KB contiguous each
    #define STAGE(st, bf)                                                     \
    {                                                                         \
        _Pragma("unroll")                                                     \
        for (int q = 0; q < 2; ++q) {                                         \
            size_t re = (size_t)(r0 + wv * 32 + (st) * 4 + q * 2);            \
            gload_lds16(W4 + (re * 16 + c) * 64 + pi, &Wl[wv][bf][q * 128]);  \
            gload_lds16(W4 + ((re + 1) * 16 + c) * 64 + pi,                   \
                        &Wl[wv][bf][q * 128 + 64]);                           \
        }                                                                     \
    }

    STAGE(0, 0);

    #pragma unroll 1
    for (int st = 0; st < 8; ++st) {
        if (st < 7) {
            STAGE(st + 1, (st + 1) & 1);
            asm volatile("s_waitcnt vmcnt(4)" ::: "memory");
        } else {
            asm volatile("s_waitcnt vmcnt(0)" ::: "memory");
        }
        const float4* Wb = &Wl[wv][st & 1][0];

        #pragma unroll
        for (int q = 0; q < 2; ++q) {
            float4 wa = Wb[q * 128 + s0];
            float4 wb = Wb[q * 128 + s1];
            float wf[8] = {wa.x, wa.y, wa.z, wa.w, wb.x, wb.y, wb.z, wb.w};
            half8_t Ah, Al;
            #pragma unroll
            for (int j = 0; j < 8; ++j) {
                _Float16 h = (_Float16)wf[j];
                Ah[j] = h;
                Al[j] = (_Float16)((wf[j] - (float)h) * 2048.0f);
            }
            if (MODE) {
                f32x16_t t = __builtin_amdgcn_mfma_f32_32x32x16_f16(Ah, Bl, z16, 0, 0, 0);
                t = __builtin_amdgcn_mfma_f32_32x32x16_f16(Al, Bh, t, 0, 0, 0);
                #pragma unroll
                for (int j = 0; j < 16; ++j) t[j] *= (1.0f / 2048.0f);
                t = __builtin_amdgcn_mfma_f32_32x32x16_f16(Ah, Bh, t, 0, 0, 0);
                float pe = 0.f, po = 0.f;
                #pragma unroll
                for (int rb = 0; rb < 4; ++rb) {
                    pe += t[rb] * vv[rb] + t[4 + rb] * vv[4 + rb];
                    po += t[8 + rb] * vv[rb] + t[12 + rb] * vv[4 + rb];
                }
                pe += __shfl_xor(pe, 32);          // join k-halves (o-halves)
                po += __shfl_xor(po, 32);
                float e0 = __expf(pe), e1 = __expf(po);
                accZ0 += e0;  accZ1 += e1;
                #pragma unroll
                for (int j = 0; j < 8; ++j)  accE[j] += e0 * t[j];
                #pragma unroll
                for (int j = 8; j < 16; ++j) accE[j] += e1 * t[j];
            } else {
                a1 = __builtin_amdgcn_mfma_f32_32x32x16_f16(Ah, Bh, a1, 0, 0, 0);
                a2 = __builtin_amdgcn_mfma_f32_32x32x16_f16(Ah, Bl, a2, 0, 0, 0);
                a2 = __builtin_amdgcn_mfma_f32_32x32x16_f16(Al, Bh, a2, 0, 0, 0);
            }
        }
    }
    #undef STAGE
    if (!MODE) {
        #pragma unroll
        for (int j = 0; j < 16; ++j) accE[j] = a1[j] + a2[j] * (1.0f / 2048.0f);
    }

    // ---- epilogue: LDS tree + atomics (red overlays the W buffers) ----
    __syncthreads();                               // all waves done with Wl
    float* red = (float*)Wl;
    float4 e0 = make_float4(accE[0] + accE[8],  accE[1] + accE[9],
                            accE[2] + accE[10], accE[3] + accE[11]);
    float4 e1 = make_float4(accE[4] + accE[12], accE[5] + accE[13],
                            accE[6] + accE[14], accE[7] + accE[15]);
    *(float4*)&red[wv * 512 + b * 16 + 4 * kh]     = e0;
    *(float4*)&red[wv * 512 + b * 16 + 8 + 4 * kh] = e1;
    if (MODE && kh == 0) red[4096 + wv * 32 + b] = accZ0 + accZ1;
    __syncthreads();
    {
        float s = 0.f;
        #pragma unroll
        for (int w2 = 0; w2 < 8; ++w2) s += red[w2 * 512 + tid];
        atomicAdd(&E[(tid >> 4) * 256 + c * 16 + (tid & 15)], s);
    }
    if (MODE && tid < 32) {
        float sz = 0.f;
        #pragma unroll
        for (int w2 = 0; w2 < 8; ++w2) sz += red[4096 + w2 * 32 + tid];
        atomicAdd(&Z[tid * 16 + c], sz);
    }
}

// ---------------------------------------------------------------------------
// launch
// ---------------------------------------------------------------------------
extern "C" void kernel_launch(void* const* d_in, const int* in_sizes, int n_in,
                              void* d_out, int out_size, void* d_ws, size_t ws_size,
                              hipStream_t stream) {
    const float* x = (const float*)d_in[0];        // 8192 floats
    const float* W = (const float*)d_in[1];        // 67108864 floats (256 MB)
    float* out = (float*)d_out;                    // 8192 floats
    float* ws = (float*)d_ws;

    float* E1   = ws + 0;          // 8192  (S = sum_r u)
    float* E2   = ws + 8192;       // 8192
    float* Z2   = ws + 16384;      // 512
    float* E3   = ws + 16896;      // 8192
    float* Z3   = ws + 25088;      // 512   (zeroed region ends at 25600)
    float* v1   = ws + 25600;      // 8192
    float* vsum = ws + 33792;      // 8192

    hipMemsetAsync(ws, 0, 25600 * sizeof(float), stream);

    // iter 1: S = sum_r u (uniform routing), W pass 1 (forward r)
    k_route<0, 0><<<dim3(16, 64), 512, 0, stream>>>(W, x, v1, E1, Z2);
    k_v1<<<32, 256, 0, stream>>>(E1, v1);          // v1 = squash(S/R)

    // iter 2: logits = <u, v1>, W pass 2 (reverse r for L3 tail reuse)
    k_route<1, 1><<<dim3(16, 64), 512, 0, stream>>>(W, x, v1, E2, Z2);
    k_vsum<<<32, 256, 0, stream>>>(E2, Z2, v1, vsum);  // vsum = v1 + squash(E2/Z2)

    // iter 3: logits = <u, v1+v2>, W pass 3 (forward r)
    k_route<1, 0><<<dim3(16, 64), 512, 0, stream>>>(W, x, vsum, E3, Z3);
    k_vout<<<32, 256, 0, stream>>>(E3, Z3, out);
}